// Round 3
// baseline (843.121 us; speedup 1.0000x reference)
//
#include <hip/hip_runtime.h>
#include <math.h>

#define DIM     2048
#define NEXP    64
#define CAP     128
#define NTOK    8192
#define NTILE   256            // 256 tiles of 32 tokens
#define BKC     128            // K-chunk for GEMM blocks
#define WROW    132            // LDS row stride for wg tile (128 + 4, 16B-multiple)

#define OUT_LAST   134217728ull   // index of last output float (out_size-1)

typedef float vfloat4 __attribute__((ext_vector_type(4)));

// One kernel, block-specialized:
//   even blocks  -> zero-fill 537 MB of combine+dispatch (pure VMEM stores)
//   odd  blocks  -> 32-token gate GEMM + softmax/argmax (VALU+LDS, no out writes)
// Per CU: ~1 zero block + ~1 gemm block co-resident; stores saturate HBM while
// FMAs run on a different pipe (m114 co-schedule). No vmcnt entanglement:
// gemm blocks issue no global stores until the tiny tail.
__global__ __launch_bounds__(256) void fused_gate(
    const float* __restrict__ x, const float* __restrict__ wg,
    float* __restrict__ out,
    int* __restrict__ expert_idx, float* __restrict__ gate_top,
    float* __restrict__ me_partial, int* __restrict__ counts)
{
    __shared__ __align__(16) float wsmem[NEXP * WROW];   // 33792 B
    __shared__ float me_w[4 * NEXP];
    __shared__ int   cnt_w[4 * NEXP];

    const int tid = threadIdx.x;
    const int b   = blockIdx.x;

    if ((b & 1) == 0) {
        // ---------------- zero-fill branch ----------------
        const int zb = b >> 1;                          // 0..255
        vfloat4* o4 = reinterpret_cast<vfloat4*>(out);  // out base is 16B-aligned
        const vfloat4 z4 = {0.f, 0.f, 0.f, 0.f};
        size_t base = (size_t)zb * 131072 + (size_t)tid;
        #pragma unroll 8
        for (int q = 0; q < 512; ++q) {
            size_t i4 = base + ((size_t)q << 8);
            if (i4 != 0)                               // f4 0 holds l_aux + combine[0..2]
                __builtin_nontemporal_store(z4, &o4[i4]);
        }
        if (zb == 0) {
            if (tid >= 1 && tid <= 3) out[tid] = 0.0f;   // combine floats 1..3
            if (tid == 4) out[OUT_LAST] = 0.0f;          // final dispatch float
        }
        return;
    }

    // ---------------- GEMM + gate branch ----------------
    const int gb   = b >> 1;                 // tile 0..255 (32 tokens)
    const int lane = tid & 63;               // lane = expert
    const int wv   = __builtin_amdgcn_readfirstlane(tid >> 6);  // wave id 0..3 (uniform)
    const int tok0 = gb * 32 + wv * 8;       // this wave's 8 tokens

    float acc[8] = {};

    for (int kc = 0; kc < DIM / BKC; ++kc) {
        const int k0 = kc * BKC;
        // stage wg[e][k0..k0+127] -> wsmem[e*WROW + k], coalesced f4 loads
        #pragma unroll
        for (int q = 0; q < 8; ++q) {
            int id = tid + (q << 8);         // 0..2047
            int e  = id >> 5;
            int c  = id & 31;
            float4 v = *(const float4*)(wg + (size_t)e * DIM + k0 + (c << 2));
            *(float4*)(&wsmem[e * WROW + (c << 2)]) = v;
        }
        __syncthreads();

        // lane's expert row from LDS; x at wave-uniform addresses (scalar/broadcast)
        #pragma unroll 4
        for (int kk = 0; kk < BKC; kk += 4) {
            float4 w4 = *(const float4*)(&wsmem[lane * WROW + kk]);
            #pragma unroll
            for (int t = 0; t < 8; ++t) {
                float4 xv = *(const float4*)(x + (size_t)(tok0 + t) * DIM + k0 + kk);
                acc[t] = fmaf(xv.x, w4.x, acc[t]);
                acc[t] = fmaf(xv.y, w4.y, acc[t]);
                acc[t] = fmaf(xv.z, w4.z, acc[t]);
                acc[t] = fmaf(xv.w, w4.w, acc[t]);
            }
        }
        __syncthreads();
    }

    // softmax + argmax across 64 lanes (lane = expert), all in registers
    float    me_acc  = 0.0f;
    int      cnt_acc = 0;
    #pragma unroll
    for (int t = 0; t < 8; ++t) {
        float v = acc[t];
        float m = v; int mi = lane;
        #pragma unroll
        for (int off = 32; off > 0; off >>= 1) {
            float om  = __shfl_xor(m, off);
            int   omi = __shfl_xor(mi, off);
            if (om > m || (om == m && omi < mi)) { m = om; mi = omi; }
        }
        float ex = __expf(v - m);
        float s  = ex;
        #pragma unroll
        for (int off = 32; off > 0; off >>= 1) s += __shfl_xor(s, off);
        me_acc += ex / s;                    // this lane's expert prob for token t
        if (lane == mi) {
            expert_idx[tok0 + t] = mi;
            gate_top[tok0 + t]   = 1.0f / s; // exp(m-m)/s
            ++cnt_acc;
        }
    }
    me_w[wv * NEXP + lane]  = me_acc;
    cnt_w[wv * NEXP + lane] = cnt_acc;
    __syncthreads();
    if (tid < NEXP) {
        me_partial[gb * NEXP + tid] = me_w[tid] + me_w[NEXP + tid]
                                    + me_w[2 * NEXP + tid] + me_w[3 * NEXP + tid];
        counts[gb * NEXP + tid]     = cnt_w[tid] + cnt_w[NEXP + tid]
                                    + cnt_w[2 * NEXP + tid] + cnt_w[3 * NEXP + tid];
    }
}

// Single block: per-expert exclusive prefix over the 256 tiles + l_aux.
__global__ __launch_bounds__(64) void prefix_laux(
    const float* __restrict__ me_partial, const int* __restrict__ counts,
    int* __restrict__ block_off, float* __restrict__ out)
{
    int e = threadIdx.x;  // one expert per lane
    float me = 0.0f;
    for (int t = 0; t < NTILE; ++t) me += me_partial[t * NEXP + e];
    int run = 0;
    for (int t = 0; t < NTILE; ++t) {
        block_off[t * NEXP + e] = run;
        run += counts[t * NEXP + e];
    }
    float ce = (float)run / (float)NTOK;
    me = me / (float)NTOK;
    float v = me * ce;
    #pragma unroll
    for (int off = 32; off > 0; off >>= 1) v += __shfl_xor(v, off);
    if (e == 0) out[0] = v * (float)NEXP;    // mean(me*ce)*E*E == sum(me*ce)*E
}

// Scatter the <=8192 nonzeros: rank within 32-token tile + tile base offset.
__global__ __launch_bounds__(64) void scatter_k(
    const int* __restrict__ expert_idx, const float* __restrict__ gate_top,
    const int* __restrict__ block_off, float* __restrict__ out)
{
    __shared__ int es[32];
    int t = threadIdx.x, b = blockIdx.x;
    if (t < 32) es[t] = expert_idx[b * 32 + t];
    __syncthreads();
    if (t < 32) {
        int e = es[t];
        int rank = 0;
        for (int u = 0; u < t; ++u) rank += (es[u] == e) ? 1 : 0;
        int loc = block_off[b * NEXP + e] + rank;
        if (loc < CAP) {
            size_t sidx = (size_t)(b * 32 + t);
            size_t off  = sidx * (NEXP * CAP) + (size_t)e * CAP + loc;
            out[1 + off] = gate_top[b * 32 + t];                     // combine
            out[1 + (size_t)NTOK * NEXP * CAP + off] = 1.0f;         // dispatch
        }
    }
}

extern "C" void kernel_launch(void* const* d_in, const int* in_sizes, int n_in,
                              void* d_out, int out_size, void* d_ws, size_t ws_size,
                              hipStream_t stream)
{
    const float* x  = (const float*)d_in[0];
    const float* wg = (const float*)d_in[1];
    float* out = (float*)d_out;

    char* ws = (char*)d_ws;
    int*   expert_idx = (int*)  (ws);            // 8192*4
    float* gate_top   = (float*)(ws + 32768);    // 8192*4
    float* me_partial = (float*)(ws + 65536);    // 256*64*4
    int*   counts     = (int*)  (ws + 131072);   // 256*64*4
    int*   block_off  = (int*)  (ws + 196608);   // 256*64*4   (total 256 KB)

    fused_gate<<<512, 256, 0, stream>>>(x, wg, out, expert_idx, gate_top,
                                        me_partial, counts);
    prefix_laux<<<1, 64, 0, stream>>>(me_partial, counts, block_off, out);
    scatter_k<<<NTILE, 64, 0, stream>>>(expert_idx, gate_top, block_off, out);
}

// Round 4
// 728.548 us; speedup vs baseline: 1.1573x; 1.1573x over previous
//
#include <hip/hip_runtime.h>
#include <math.h>

#define DIM     2048
#define NEXP    64
#define CAP     128
#define NTOK    8192
#define NTILE   256            // 256 tiles of 32 tokens
#define BKC     128            // K-chunk for gate GEMM
#define WROW    132            // LDS row stride (128+4 floats): 16B-aligned, no extra conflicts (measured 0 in R3)

#define OUT_LAST   134217728ull   // last output float index (out_size-1)
#define NF4        33554432ull    // float4s covering floats [0, 134217728)

typedef float vfloat4 __attribute__((ext_vector_type(4)));

// ---------------- 1. zero-fill: 537 MB of combine+dispatch ----------------
// 2048 blocks x 256 thr -> 8 blocks/CU on every XCD regardless of the
// (undefined) blockIdx->XCD mapping. Structure mirrors the harness fill
// that measured 6.23 TB/s. 64 float4 per thread, contiguous per-q slabs.
__global__ __launch_bounds__(256) void fill_out(float* __restrict__ out)
{
    vfloat4* o4 = reinterpret_cast<vfloat4*>(out);
    const vfloat4 z4 = {0.f, 0.f, 0.f, 0.f};
    size_t base = (size_t)blockIdx.x * 16384 + threadIdx.x;
    #pragma unroll 16
    for (int q = 0; q < 64; ++q)
        __builtin_nontemporal_store(z4, &o4[base + ((size_t)q << 8)]);
    if (blockIdx.x == 0 && threadIdx.x == 0)
        out[OUT_LAST] = 0.0f;            // the one float not covered by float4s
    // out[0] (l_aux) is zeroed here and overwritten by prefix_laux later.
}

// ---------------- 2. gate GEMM + softmax + argmax ----------------
// 256 blocks x 512 thr: 8 waves (2/SIMD). lane = expert; wave wv owns 4 tokens.
// wg tile [64][128] staged in LDS (coalesced f4); x read at wave-uniform
// addresses (scalar-cache path). fp32 FMA floor: 1.07e9 FMA / 157 TF = 14 us.
__global__ __launch_bounds__(512) void gate_kernel(
    const float* __restrict__ x, const float* __restrict__ wg,
    int* __restrict__ expert_idx, float* __restrict__ gate_top,
    float* __restrict__ me_partial, int* __restrict__ counts)
{
    __shared__ __align__(16) float wsmem[NEXP * WROW];   // 33792 B
    __shared__ float me_w[8 * NEXP];
    __shared__ int   cnt_w[8 * NEXP];

    const int tid  = threadIdx.x;
    const int gb   = blockIdx.x;
    const int lane = tid & 63;                                  // expert
    const int wv   = __builtin_amdgcn_readfirstlane(tid >> 6);  // wave 0..7
    const int tok0 = gb * 32 + wv * 4;                          // 4 tokens/wave

    float acc[4] = {};

    for (int kc = 0; kc < DIM / BKC; ++kc) {
        const int k0 = kc * BKC;
        // stage wg[e][k0..k0+127]: 2048 f4, 4 per thread, coalesced
        #pragma unroll
        for (int q = 0; q < 4; ++q) {
            int id = tid + (q << 9);         // 0..2047
            int e  = id >> 5;
            int c  = id & 31;
            float4 v = *(const float4*)(wg + (size_t)e * DIM + k0 + (c << 2));
            *(float4*)(&wsmem[e * WROW + (c << 2)]) = v;
        }
        __syncthreads();

        #pragma unroll 8
        for (int kk = 0; kk < BKC; kk += 4) {
            float4 w4 = *(const float4*)(&wsmem[lane * WROW + kk]);
            #pragma unroll
            for (int t = 0; t < 4; ++t) {
                float4 xv = *(const float4*)(x + (size_t)(tok0 + t) * DIM + k0 + kk);
                acc[t] = fmaf(xv.x, w4.x, acc[t]);
                acc[t] = fmaf(xv.y, w4.y, acc[t]);
                acc[t] = fmaf(xv.z, w4.z, acc[t]);
                acc[t] = fmaf(xv.w, w4.w, acc[t]);
            }
        }
        __syncthreads();
    }

    // softmax + argmax across 64 lanes (lane = expert), registers only
    float me_acc  = 0.0f;
    int   cnt_acc = 0;
    #pragma unroll
    for (int t = 0; t < 4; ++t) {
        float v = acc[t];
        float m = v; int mi = lane;
        #pragma unroll
        for (int off = 32; off > 0; off >>= 1) {
            float om  = __shfl_xor(m, off);
            int   omi = __shfl_xor(mi, off);
            if (om > m || (om == m && omi < mi)) { m = om; mi = omi; }
        }
        float ex = __expf(v - m);
        float s  = ex;
        #pragma unroll
        for (int off = 32; off > 0; off >>= 1) s += __shfl_xor(s, off);
        me_acc += ex / s;
        if (lane == mi) {
            expert_idx[tok0 + t] = mi;
            gate_top[tok0 + t]   = 1.0f / s;  // exp(m-m)/s
            ++cnt_acc;
        }
    }
    me_w[wv * NEXP + lane]  = me_acc;
    cnt_w[wv * NEXP + lane] = cnt_acc;
    __syncthreads();
    if (tid < NEXP) {
        float ms = 0.f; int cs = 0;
        #pragma unroll
        for (int w = 0; w < 8; ++w) { ms += me_w[w * NEXP + tid]; cs += cnt_w[w * NEXP + tid]; }
        me_partial[gb * NEXP + tid] = ms;
        counts[gb * NEXP + tid]     = cs;
    }
}

// ---------------- 3. two-level prefix over 256 tiles + l_aux ----------------
// 1 block x 1024 thr: thread (e = tid&63, g = tid>>6) sums 16 tiles; 16-group
// exclusive scan per expert in LDS; re-walk own 16 tiles for block_off.
__global__ __launch_bounds__(1024) void prefix_laux(
    const float* __restrict__ me_partial, const int* __restrict__ counts,
    int* __restrict__ block_off, float* __restrict__ out)
{
    __shared__ int   cnt_l[16 * NEXP];
    __shared__ float me_l[16 * NEXP];
    __shared__ int   cnt_tot[NEXP];
    __shared__ float me_tot[NEXP];

    const int tid = threadIdx.x;
    const int e   = tid & 63;
    const int g   = tid >> 6;          // 0..15

    int   cs = 0; float ms = 0.f;
    #pragma unroll
    for (int i = 0; i < 16; ++i) {
        int t = g * 16 + i;
        cs += counts[t * NEXP + e];
        ms += me_partial[t * NEXP + e];
    }
    cnt_l[g * NEXP + e] = cs;
    me_l[g * NEXP + e]  = ms;
    __syncthreads();

    if (g == 0) {                      // 64 threads: serial scan of 16 groups
        int run = 0; float mt = 0.f;
        #pragma unroll
        for (int i = 0; i < 16; ++i) {
            int c = cnt_l[i * NEXP + e];
            cnt_l[i * NEXP + e] = run;
            run += c;
            mt  += me_l[i * NEXP + e];
        }
        cnt_tot[e] = run;
        me_tot[e]  = mt;
    }
    __syncthreads();

    int run = cnt_l[g * NEXP + e];
    #pragma unroll
    for (int i = 0; i < 16; ++i) {
        int t = g * 16 + i;
        block_off[t * NEXP + e] = run;
        run += counts[t * NEXP + e];   // L2-hot second read
    }

    if (tid < NEXP) {
        float v = (me_tot[e] / (float)NTOK) * ((float)cnt_tot[e] / (float)NTOK);
        #pragma unroll
        for (int off = 32; off > 0; off >>= 1) v += __shfl_xor(v, off);
        if (e == 0) out[0] = v * (float)NEXP;   // mean(me*ce)*E*E == sum*E
    }
}

// ---------------- 4. scatter the <=8192 nonzeros ----------------
__global__ __launch_bounds__(64) void scatter_k(
    const int* __restrict__ expert_idx, const float* __restrict__ gate_top,
    const int* __restrict__ block_off, float* __restrict__ out)
{
    __shared__ int es[32];
    int t = threadIdx.x, b = blockIdx.x;
    if (t < 32) es[t] = expert_idx[b * 32 + t];
    __syncthreads();
    if (t < 32) {
        int e = es[t];
        int rank = 0;
        for (int u = 0; u < t; ++u) rank += (es[u] == e) ? 1 : 0;
        int loc = block_off[b * NEXP + e] + rank;
        if (loc < CAP) {
            size_t sidx = (size_t)(b * 32 + t);
            size_t off  = sidx * (NEXP * CAP) + (size_t)e * CAP + loc;
            out[1 + off] = gate_top[b * 32 + t];                 // combine
            out[1 + (size_t)NTOK * NEXP * CAP + off] = 1.0f;     // dispatch
        }
    }
}

extern "C" void kernel_launch(void* const* d_in, const int* in_sizes, int n_in,
                              void* d_out, int out_size, void* d_ws, size_t ws_size,
                              hipStream_t stream)
{
    const float* x  = (const float*)d_in[0];
    const float* wg = (const float*)d_in[1];
    float* out = (float*)d_out;

    char* ws = (char*)d_ws;
    int*   expert_idx = (int*)  (ws);            // 8192*4
    float* gate_top   = (float*)(ws + 32768);    // 8192*4
    float* me_partial = (float*)(ws + 65536);    // 256*64*4
    int*   counts     = (int*)  (ws + 131072);   // 256*64*4
    int*   block_off  = (int*)  (ws + 196608);   // 256*64*4   (total 256 KB)

    fill_out<<<2048, 256, 0, stream>>>(out);
    gate_kernel<<<NTILE, 512, 0, stream>>>(x, wg, expert_idx, gate_top,
                                           me_partial, counts);
    prefix_laux<<<1, 1024, 0, stream>>>(me_partial, counts, block_off, out);
    scatter_k<<<NTILE, 64, 0, stream>>>(expert_idx, gate_top, block_off, out);
}

// Round 5
// 615.533 us; speedup vs baseline: 1.3697x; 1.1836x over previous
//
#include <hip/hip_runtime.h>
#include <math.h>

#define DIM     2048
#define NEXP    64
#define CAP     128
#define NTOK    8192
#define NTILE   256            // 256 tiles of 32 tokens
#define KC      256            // K-chunk staged in LDS
#define NCH     (DIM/KC)       // 8 chunks
#define XWSTR   260            // row stride for xs/ws tiles (KC+4)
#define PSTR    68             // row stride for partial/logit tiles

#define OUT_LAST   134217728ull   // last output float index (out_size-1)

typedef float vfloat4 __attribute__((ext_vector_type(4)));

// ---------------- 1. zero-fill: 537 MB of combine+dispatch ----------------
__global__ __launch_bounds__(256) void fill_out(float* __restrict__ out)
{
    vfloat4* o4 = reinterpret_cast<vfloat4*>(out);
    const vfloat4 z4 = {0.f, 0.f, 0.f, 0.f};
    size_t base = (size_t)blockIdx.x * 16384 + threadIdx.x;
    #pragma unroll 16
    for (int q = 0; q < 64; ++q)
        __builtin_nontemporal_store(z4, &o4[base + ((size_t)q << 8)]);
    if (blockIdx.x == 0 && threadIdx.x == 0)
        out[OUT_LAST] = 0.0f;            // the one float past the float4 span
}

// ---------------- 2. gate GEMM + softmax + argmax ----------------
// 256 blocks x 256 thr, tile 32 tok x 64 exp, K-sliced 8-way.
// Thread (s = tid>>5, tg = tid&3, eg = (tid&31)>>2) owns tokens tg+4j,
// experts eg+8m (j,m in 0..7) over kk in [s*32,(s+1)*32) of each chunk.
// Both operands from LDS b128; NO same-address global loads in the hot loop
// (that was the R3/R4 disaster: ~2048 latency-serialized broadcast loads/thr).
__global__ __launch_bounds__(256, 1) void gate_kernel(
    const float* __restrict__ x, const float* __restrict__ wg,
    int* __restrict__ expert_idx, float* __restrict__ gate_top,
    float* __restrict__ me_partial, int* __restrict__ counts)
{
    // 96 rows * 260 floats = 99,840 B; reused for partials+logits after GEMM
    __shared__ __align__(16) float smem[(32 + NEXP) * XWSTR];
    __shared__ float me_w[4 * NEXP];
    __shared__ int   cnt_w[4 * NEXP];

    float* xs = smem;                 // [32][XWSTR]
    float* ws = smem + 32 * XWSTR;    // [64][XWSTR]

    const int tid  = threadIdx.x;
    const int gb   = blockIdx.x;
    const int tok0 = gb * 32;
    const int s    = tid >> 5;        // k-slice 0..7
    const int i    = tid & 31;
    const int tg   = i & 3;           // token group
    const int eg   = i >> 2;          // expert group 0..7
    const int kb   = s * 32;          // slice's kk base within chunk

    float acc[8][8] = {};

    for (int ch = 0; ch < NCH; ++ch) {
        const int k0 = ch * KC;
        // stage x tile [32][KC]: 2048 f4, 8 per thread, coalesced rows
        #pragma unroll
        for (int q = 0; q < 8; ++q) {
            int id = tid + (q << 8);
            int r = id >> 6, c = id & 63;
            float4 v = *(const float4*)(x + (size_t)(tok0 + r) * DIM + k0 + 4 * c);
            *(float4*)(&xs[r * XWSTR + 4 * c]) = v;
        }
        // stage w tile [64][KC]: 4096 f4, 16 per thread
        #pragma unroll
        for (int q = 0; q < 16; ++q) {
            int id = tid + (q << 8);
            int r = id >> 6, c = id & 63;
            float4 v = *(const float4*)(wg + (size_t)r * DIM + k0 + 4 * c);
            *(float4*)(&ws[r * XWSTR + 4 * c]) = v;
        }
        __syncthreads();

        for (int q2 = 0; q2 < 8; ++q2) {        // 4-kk steps
            const int kk = kb + 4 * q2;
            float4 xt[8], we[8];
            #pragma unroll
            for (int j = 0; j < 8; ++j)
                xt[j] = *(const float4*)(&xs[(tg + 4 * j) * XWSTR + kk]);
            #pragma unroll
            for (int m = 0; m < 8; ++m)
                we[m] = *(const float4*)(&ws[(eg + 8 * m) * XWSTR + kk]);
            #pragma unroll
            for (int j = 0; j < 8; ++j)
                #pragma unroll
                for (int m = 0; m < 8; ++m) {
                    acc[j][m] = fmaf(xt[j].x, we[m].x, acc[j][m]);
                    acc[j][m] = fmaf(xt[j].y, we[m].y, acc[j][m]);
                    acc[j][m] = fmaf(xt[j].z, we[m].z, acc[j][m]);
                    acc[j][m] = fmaf(xt[j].w, we[m].w, acc[j][m]);
                }
        }
        __syncthreads();
    }

    // ---- reduce the 8 k-slices through LDS (reuse smem) ----
    float* part = smem;               // [8][32][PSTR] = 17408 floats
    float* lgt  = smem + 8 * 32 * PSTR; // [32][PSTR]
    #pragma unroll
    for (int j = 0; j < 8; ++j)
        #pragma unroll
        for (int m = 0; m < 8; ++m)
            part[(s * 32 + tg + 4 * j) * PSTR + eg + 8 * m] = acc[j][m];
    __syncthreads();

    {
        int t  = tid >> 3;
        int e0 = (tid & 7) * 8;
        float4 a0 = {0,0,0,0}, a1 = {0,0,0,0};
        #pragma unroll
        for (int s2 = 0; s2 < 8; ++s2) {
            float4 p0 = *(const float4*)(&part[(s2 * 32 + t) * PSTR + e0]);
            float4 p1 = *(const float4*)(&part[(s2 * 32 + t) * PSTR + e0 + 4]);
            a0.x += p0.x; a0.y += p0.y; a0.z += p0.z; a0.w += p0.w;
            a1.x += p1.x; a1.y += p1.y; a1.z += p1.z; a1.w += p1.w;
        }
        __syncthreads();              // all partial reads done before overwrite
        *(float4*)(&lgt[t * PSTR + e0])     = a0;
        *(float4*)(&lgt[t * PSTR + e0 + 4]) = a1;
    }
    __syncthreads();

    // ---- softmax + argmax: 4 waves x 8 rows, lane = expert (R1-proven) ----
    const int lane = tid & 63;
    const int wv   = tid >> 6;
    float me_acc  = 0.0f;
    int   cnt_acc = 0;
    for (int r8 = 0; r8 < 8; ++r8) {
        int row = wv * 8 + r8;
        float v = lgt[row * PSTR + lane];
        float m = v; int mi = lane;
        #pragma unroll
        for (int off = 32; off > 0; off >>= 1) {
            float om  = __shfl_xor(m, off);
            int   omi = __shfl_xor(mi, off);
            if (om > m || (om == m && omi < mi)) { m = om; mi = omi; }
        }
        float ex = __expf(v - m);
        float sm = ex;
        #pragma unroll
        for (int off = 32; off > 0; off >>= 1) sm += __shfl_xor(sm, off);
        me_acc += ex / sm;
        if (lane == mi) {
            expert_idx[tok0 + row] = mi;
            gate_top[tok0 + row]   = 1.0f / sm;
            ++cnt_acc;
        }
    }
    me_w[wv * NEXP + lane]  = me_acc;
    cnt_w[wv * NEXP + lane] = cnt_acc;
    __syncthreads();
    if (tid < NEXP) {
        me_partial[gb * NEXP + tid] = me_w[tid] + me_w[NEXP + tid]
                                    + me_w[2 * NEXP + tid] + me_w[3 * NEXP + tid];
        counts[gb * NEXP + tid]     = cnt_w[tid] + cnt_w[NEXP + tid]
                                    + cnt_w[2 * NEXP + tid] + cnt_w[3 * NEXP + tid];
    }
}

// ---------------- 3. two-level prefix over 256 tiles + l_aux ----------------
__global__ __launch_bounds__(1024) void prefix_laux(
    const float* __restrict__ me_partial, const int* __restrict__ counts,
    int* __restrict__ block_off, float* __restrict__ out)
{
    __shared__ int   cnt_l[16 * NEXP];
    __shared__ float me_l[16 * NEXP];
    __shared__ int   cnt_tot[NEXP];
    __shared__ float me_tot[NEXP];

    const int tid = threadIdx.x;
    const int e   = tid & 63;
    const int g   = tid >> 6;          // 0..15

    int cs = 0; float ms = 0.f;
    #pragma unroll
    for (int i = 0; i < 16; ++i) {
        int t = g * 16 + i;
        cs += counts[t * NEXP + e];
        ms += me_partial[t * NEXP + e];
    }
    cnt_l[g * NEXP + e] = cs;
    me_l[g * NEXP + e]  = ms;
    __syncthreads();

    if (g == 0) {
        int run = 0; float mt = 0.f;
        #pragma unroll
        for (int i = 0; i < 16; ++i) {
            int c = cnt_l[i * NEXP + e];
            cnt_l[i * NEXP + e] = run;
            run += c;
            mt  += me_l[i * NEXP + e];
        }
        cnt_tot[e] = run;
        me_tot[e]  = mt;
    }
    __syncthreads();

    int run = cnt_l[g * NEXP + e];
    #pragma unroll
    for (int i = 0; i < 16; ++i) {
        int t = g * 16 + i;
        block_off[t * NEXP + e] = run;
        run += counts[t * NEXP + e];
    }

    if (tid < NEXP) {
        float v = (me_tot[e] / (float)NTOK) * ((float)cnt_tot[e] / (float)NTOK);
        #pragma unroll
        for (int off = 32; off > 0; off >>= 1) v += __shfl_xor(v, off);
        if (e == 0) out[0] = v * (float)NEXP;   // mean(me*ce)*E*E == sum*E
    }
}

// ---------------- 4. scatter the <=8192 nonzeros ----------------
__global__ __launch_bounds__(64) void scatter_k(
    const int* __restrict__ expert_idx, const float* __restrict__ gate_top,
    const int* __restrict__ block_off, float* __restrict__ out)
{
    __shared__ int es[32];
    int t = threadIdx.x, b = blockIdx.x;
    if (t < 32) es[t] = expert_idx[b * 32 + t];
    __syncthreads();
    if (t < 32) {
        int e = es[t];
        int rank = 0;
        for (int u = 0; u < t; ++u) rank += (es[u] == e) ? 1 : 0;
        int loc = block_off[b * NEXP + e] + rank;
        if (loc < CAP) {
            size_t sidx = (size_t)(b * 32 + t);
            size_t off  = sidx * (NEXP * CAP) + (size_t)e * CAP + loc;
            out[1 + off] = gate_top[b * 32 + t];                 // combine
            out[1 + (size_t)NTOK * NEXP * CAP + off] = 1.0f;     // dispatch
        }
    }
}

extern "C" void kernel_launch(void* const* d_in, const int* in_sizes, int n_in,
                              void* d_out, int out_size, void* d_ws, size_t ws_size,
                              hipStream_t stream)
{
    const float* x  = (const float*)d_in[0];
    const float* wg = (const float*)d_in[1];
    float* out = (float*)d_out;

    char* ws = (char*)d_ws;
    int*   expert_idx = (int*)  (ws);            // 8192*4
    float* gate_top   = (float*)(ws + 32768);    // 8192*4
    float* me_partial = (float*)(ws + 65536);    // 256*64*4
    int*   counts     = (int*)  (ws + 131072);   // 256*64*4
    int*   block_off  = (int*)  (ws + 196608);   // 256*64*4   (total 256 KB)

    fill_out<<<2048, 256, 0, stream>>>(out);
    gate_kernel<<<NTILE, 256, 0, stream>>>(x, wg, expert_idx, gate_top,
                                           me_partial, counts);
    prefix_laux<<<1, 1024, 0, stream>>>(me_partial, counts, block_off, out);
    scatter_k<<<NTILE, 64, 0, stream>>>(expert_idx, gate_top, block_off, out);
}